// Round 7
// baseline (225.172 us; speedup 1.0000x reference)
//
#include <hip/hip_runtime.h>
#include <math.h>

// YOLOX loss, fixed shapes: B=32, A = 80*80 + 40*40 + 20*20 = 8400, 85 channels.
constexpr int A_TOTAL = 8400;
constexpr int AGPI    = A_TOTAL / 4;   // anchor-groups per image = 2100

// clang native vectors (HIP float4 is a struct; the nontemporal builtin
// requires real vector / scalar types)
typedef float v4f __attribute__((ext_vector_type(4)));
typedef int   v4i __attribute__((ext_vector_type(4)));

__device__ __forceinline__ float bce(float x, float t) {
    // max(x,0) - x*t + softplus(-|x|); hw exp/log (v_exp_f32/v_log_f32)
    float ax = fabsf(x);
    float sp = __logf(1.0f + __expf(-ax));
    return fmaxf(x, 0.0f) - x * t + sp;
}

// Non-temporal load wrappers: emit global_load_* with the nt flag -> bypass L1
// allocation. Theory: per-CU L1 miss-tracking (~20 lines) is the concurrency
// cap pinning all prior rounds at ~74 us; nt moves miss tracking to vmcnt/L2.
__device__ __forceinline__ v4f ntload4(const float* p) {
    return __builtin_nontemporal_load(reinterpret_cast<const v4f*>(p));
}
__device__ __forceinline__ v4i ntloadi4(const int* p) {
    return __builtin_nontemporal_load(reinterpret_cast<const v4i*>(p));
}

// Fused kernel. Thread layout: t = ag*4 + q.
//   ag = global anchor group (4 consecutive anchors), q = class quarter.
// Each thread: cls BCE for 4 anchors x 20 classes (float4 loads both sides)
//              + IoU/obj for anchor a0+q (balanced across q).
__global__ __launch_bounds__(256) void yolox_fused(
    const float* __restrict__ out0, const float* __restrict__ out1,
    const float* __restrict__ out2, const float* __restrict__ regt,
    const float* __restrict__ clst, const int* __restrict__ fgm,
    double* __restrict__ acc, int B)
{
    int t  = blockIdx.x * blockDim.x + threadIdx.x;
    int q  = t & 3;
    int ag = t >> 2;
    int b  = ag / AGPI;
    int rg = ag - b * AGPI;
    int a0 = rg * 4;                       // anchor index within image (mult of 4)

    const float* obase; int HW; float stride; int al; int W;
    if (a0 < 6400)      { obase = out0 + (size_t)b * 85 * 6400; HW = 6400; stride = 8.0f;  al = a0;        W = 80; }
    else if (a0 < 8000) { obase = out1 + (size_t)b * 85 * 1600; HW = 1600; stride = 16.0f; al = a0 - 6400; W = 40; }
    else                { obase = out2 + (size_t)b * 85 * 400;  HW = 400;  stride = 32.0f; al = a0 - 8000; W = 20; }

    // ---- cls logits: 20 x float4 across 4 consecutive anchors (16B/lane) ----
    v4f L[20];
    const float* cb = obase + (size_t)(5 + q * 20) * HW + al;
    #pragma unroll
    for (int i = 0; i < 20; ++i)
        L[i] = ntload4(cb + (size_t)i * HW);

    // fg for the 4 anchors (one int4)
    v4i fg4 = ntloadi4(fgm + (size_t)b * A_TOTAL + a0);
    float fgf[4] = { (float)fg4.x, (float)fg4.y, (float)fg4.z, (float)fg4.w };

    // ---- cls BCE: per anchor j, 20 classes ----
    float local = 0.0f;
    #pragma unroll
    for (int j = 0; j < 4; ++j) {
        const float* tp = clst + ((size_t)b * A_TOTAL + a0 + j) * 80 + q * 20;
        float tg[20];
        #pragma unroll
        for (int i5 = 0; i5 < 5; ++i5) {
            v4f tv = ntload4(tp + 4 * i5);
            tg[4 * i5 + 0] = tv.x; tg[4 * i5 + 1] = tv.y;
            tg[4 * i5 + 2] = tv.z; tg[4 * i5 + 3] = tv.w;
        }
        float s = 0.0f;
        #pragma unroll
        for (int i = 0; i < 20; ++i)
            s += bce(L[i][j], tg[i]);
        local += s * fgf[j];
    }

    // ---- IoU + objectness for anchor a0+q ----
    {
        int aa  = al + q;                   // local anchor within level
        int a   = a0 + q;                   // image anchor
        int gx  = aa % W;
        int gy  = aa / W;
        float tx   = obase[aa];
        float ty   = obase[(size_t)1 * HW + aa];
        float tw   = obase[(size_t)2 * HW + aa];
        float th   = obase[(size_t)3 * HW + aa];
        float tobj = obase[(size_t)4 * HW + aa];

        float px = (tx + (float)gx) * stride;
        float py = (ty + (float)gy) * stride;
        float pw = __expf(tw) * stride;
        float ph = __expf(th) * stride;

        v4f rt = ntload4(regt + ((size_t)b * A_TOTAL + a) * 4);
        float fgv = fgf[q];

        float tlx = fmaxf(px - pw * 0.5f, rt.x - rt.z * 0.5f);
        float tly = fmaxf(py - ph * 0.5f, rt.y - rt.w * 0.5f);
        float brx = fminf(px + pw * 0.5f, rt.x + rt.z * 0.5f);
        float bry = fminf(py + ph * 0.5f, rt.y + rt.w * 0.5f);
        float area_p = pw * ph;
        float area_g = rt.z * rt.w;
        float en = ((tlx < brx) && (tly < bry)) ? 1.0f : 0.0f;
        float area_i = (brx - tlx) * (bry - tly) * en;
        float area_u = area_p + area_g - area_i;
        float iou = area_i / (area_u + 1e-16f);
        float l_iou = 1.0f - iou * iou;

        local += 5.0f * l_iou * fgv + bce(tobj, fgv);
        float fgl = fgv;

        // ---- block reduction + atomics ----
        for (int off = 32; off > 0; off >>= 1) {
            local += __shfl_down(local, off, 64);
            fgl   += __shfl_down(fgl,   off, 64);
        }
        __shared__ float s_v[4], s_w[4];
        int wid  = threadIdx.x >> 6;
        int lane = threadIdx.x & 63;
        if (lane == 0) { s_v[wid] = local; s_w[wid] = fgl; }
        __syncthreads();
        if (threadIdx.x == 0) {
            atomicAdd(&acc[0], (double)(s_v[0] + s_v[1] + s_v[2] + s_v[3]));
            atomicAdd(&acc[1], (double)(s_w[0] + s_w[1] + s_w[2] + s_w[3]));
        }
    }
}

__global__ void yolox_final(const double* __restrict__ acc, float* __restrict__ out) {
    out[0] = (float)(acc[0] / fmax(acc[1], 1.0));
}

extern "C" void kernel_launch(void* const* d_in, const int* in_sizes, int n_in,
                              void* d_out, int out_size, void* d_ws, size_t ws_size,
                              hipStream_t stream) {
    const float* out0 = (const float*)d_in[0];
    const float* out1 = (const float*)d_in[1];
    const float* out2 = (const float*)d_in[2];
    const float* regt = (const float*)d_in[3];
    const float* clst = (const float*)d_in[4];
    const int*   fgm  = (const int*)d_in[5];

    int B = in_sizes[0] / (85 * 6400);
    double* acc = (double*)d_ws;
    (void)hipMemsetAsync(acc, 0, 2 * sizeof(double), stream);

    int total  = B * A_TOTAL;                 // one thread per (anchor-group, quarter)
    int blocks = (total + 255) / 256;         // 1050 blocks for B=32
    hipLaunchKernelGGL(yolox_fused, dim3(blocks), dim3(256), 0, stream,
                       out0, out1, out2, regt, clst, fgm, acc, B);
    hipLaunchKernelGGL(yolox_final, dim3(1), dim3(1), 0, stream, acc, (float*)d_out);
}